// Round 5
// baseline (1152.278 us; speedup 1.0000x reference)
//
#include <hip/hip_runtime.h>

#define H 128
#define FN 16
#define FE 8
#define NBUK_MAX 1600   // buckets = ceil(N/64) = 1563 for N=100k

// ============================ histogram (both sorts fused) ============================
__global__ __launch_bounds__(256) void k_hist2(
    const int* __restrict__ k1, const int* __restrict__ k2,
    int* __restrict__ bcnt1, int* __restrict__ bcnt2, int E, int nbuk) {
  __shared__ int h1[NBUK_MAX], h2[NBUK_MAX];
  for (int i = threadIdx.x; i < nbuk; i += 256) { h1[i] = 0; h2[i] = 0; }
  __syncthreads();
  for (int e = blockIdx.x * 256 + threadIdx.x; e < E; e += gridDim.x * 256) {
    atomicAdd(&h1[k1[e] >> 6], 1);
    atomicAdd(&h2[k2[e] >> 6], 1);
  }
  __syncthreads();
  for (int i = threadIdx.x; i < nbuk; i += 256) {
    if (h1[i]) atomicAdd(&bcnt1[i], h1[i]);
    if (h2[i]) atomicAdd(&bcnt2[i], h2[i]);
  }
}

// ============================ single-block dual scan ============================
// Exclusive-scans cnt1 -> st1 (+copy gc1) and cnt2 -> st2 (+gc2); st[nbuk]=total.
__global__ __launch_bounds__(1024) void k_scan(
    const int* __restrict__ cnt1, int* __restrict__ st1, int* __restrict__ gc1,
    const int* __restrict__ cnt2, int* __restrict__ st2, int* __restrict__ gc2,
    int nbuk) {
  __shared__ int s[1024];
  int tid = threadIdx.x;
  for (int pass = 0; pass < 2; pass++) {
    const int* cnt = pass ? cnt2 : cnt1;
    int* st = pass ? st2 : st1;
    int* gc = pass ? gc2 : gc1;
    int run = 0;
    for (int half = 0; half * 1024 < nbuk; half++) {
      int i = half * 1024 + tid;
      int v = (i < nbuk) ? cnt[i] : 0;
      s[tid] = v; __syncthreads();
      for (int off = 1; off < 1024; off <<= 1) {
        int t = (tid >= off) ? s[tid - off] : 0;
        __syncthreads();
        s[tid] += t;
        __syncthreads();
      }
      int excl = run + s[tid] - v;
      if (i < nbuk) { st[i] = excl; gc[i] = excl; }
      run += s[1023];
      __syncthreads();   // protect s before next half overwrites
    }
    if (tid == 0) st[nbuk] = run;
    __syncthreads();
  }
}

// ============================ pass-1 bucket scatter ============================
// PACKED=1: write (e<<6)|(key&63) single int (embed sort).
// PACKED=0: write int2( dst | (key&63)<<20 , val_bits ) (adj sort).
template <int PACKED>
__global__ __launch_bounds__(256) void k_p1_scatter(
    const int* __restrict__ key, const int* __restrict__ dsts,
    const float* __restrict__ vals, int* __restrict__ gcur,
    int* __restrict__ pkey, int2* __restrict__ bpay, int E, int nbuk) {
  __shared__ int hc[NBUK_MAX];
  int tid = threadIdx.x;
  int c0 = blockIdx.x * 8192;
  int c1 = min(c0 + 8192, E);
  for (int i = tid; i < nbuk; i += 256) hc[i] = 0;
  __syncthreads();
  for (int e = c0 + tid; e < c1; e += 256)
    atomicAdd(&hc[key[e] >> 6], 1);
  __syncthreads();
  for (int i = tid; i < nbuk; i += 256) {
    int c = hc[i];
    if (c) hc[i] = atomicAdd(&gcur[i], c);   // becomes this block's base cursor
  }
  __syncthreads();
  for (int e = c0 + tid; e < c1; e += 256) {
    int k = key[e];
    int pos = atomicAdd(&hc[k >> 6], 1);
    if (PACKED) {
      pkey[pos] = (e << 6) | (k & 63);
    } else {
      bpay[pos] = make_int2(dsts[e] | ((k & 63) << 20), __float_as_int(vals[e]));
    }
  }
}

// ============================ embed bucket-sum (replaces p2 + gather) ============================
// agg8[node] = sum of edge_attr rows whose dst is in this bucket's 64-node range.
__global__ __launch_bounds__(256) void k_embed_agg(
    const int* __restrict__ pkey, const float* __restrict__ edge_attr,
    const int* __restrict__ bstart, float* __restrict__ agg8, int N) {
  __shared__ float lds[FE][64];   // f-major: bank = slot%32, random slots ~conflict-free
  int b = blockIdx.x, tid = threadIdx.x;
  for (int i = tid; i < FE * 64; i += 256) ((float*)lds)[i] = 0.f;
  __syncthreads();
  int s = bstart[b], t = bstart[b + 1];
  for (int i = s + tid; i < t; i += 256) {
    int pk = pkey[i];
    int e = pk >> 6, slot = pk & 63;
    const float4* ea = (const float4*)(edge_attr + (size_t)e * FE);
    float4 a = ea[0], b4 = ea[1];
    atomicAdd(&lds[0][slot], a.x);  atomicAdd(&lds[1][slot], a.y);
    atomicAdd(&lds[2][slot], a.z);  atomicAdd(&lds[3][slot], a.w);
    atomicAdd(&lds[4][slot], b4.x); atomicAdd(&lds[5][slot], b4.y);
    atomicAdd(&lds[6][slot], b4.z); atomicAdd(&lds[7][slot], b4.w);
  }
  __syncthreads();
  int node0 = b * 64;
  for (int i = tid; i < 64 * FE; i += 256) {
    int n = node0 + (i >> 3);
    if (n < N) agg8[(size_t)n * FE + (i & 7)] = lds[i & 7][i >> 3];
  }
}

// ============================ pass-2 for adj sort ============================
__global__ __launch_bounds__(256) void k_p2(
    const int2* __restrict__ bpay, const int* __restrict__ bstart,
    int* __restrict__ offs, int2* __restrict__ payF, int N, int E) {
  __shared__ int cnt[64], scn[64], cur[64];
  int b = blockIdx.x, tid = threadIdx.x;
  int s = bstart[b], t = bstart[b + 1];
  if (tid < 64) cnt[tid] = 0;
  __syncthreads();
  for (int i = s + tid; i < t; i += 256) atomicAdd(&cnt[(bpay[i].x >> 20) & 63], 1);
  __syncthreads();
  if (tid < 64) scn[tid] = cnt[tid];
  __syncthreads();
  for (int off = 1; off < 64; off <<= 1) {
    int v = 0;
    if (tid < 64 && tid >= off) v = scn[tid - off];
    __syncthreads();
    if (tid < 64 && tid >= off) scn[tid] += v;
    __syncthreads();
  }
  if (tid < 64) {
    int excl = s + scn[tid] - cnt[tid];
    cur[tid] = excl;
    int node = b * 64 + tid;
    if (node < N) offs[node] = excl;
  }
  if (b == 0 && tid == 0) offs[N] = E;
  __syncthreads();
  for (int i = s + tid; i < t; i += 256) {
    int2 p = bpay[i];
    int slot = (p.x >> 20) & 63;
    int pos = atomicAdd(&cur[slot], 1);
    payF[pos] = make_int2(p.x & 0xFFFFF, p.y);
  }
}

// ============================ embed h ============================
__global__ __launch_bounds__(256) void k_embed_h(
    const float* __restrict__ node_attr, const float* __restrict__ Wn,
    const float* __restrict__ We8, const float* __restrict__ b,
    const float* __restrict__ agg8, float* __restrict__ h, int N) {
  __shared__ float Ws[FN * H];
  __shared__ float Es[FE * H];
  __shared__ float na[2][FN];
  __shared__ float a8[2][FE];
  for (int i = threadIdx.x; i < FN * H; i += 256) Ws[i] = Wn[i];
  for (int i = threadIdx.x; i < FE * H; i += 256) Es[i] = We8[i];
  int lane = threadIdx.x & 127;
  int sub  = threadIdx.x >> 7;
  for (int n0 = blockIdx.x * 2; n0 < N; n0 += gridDim.x * 2) {
    int n = n0 + sub;
    __syncthreads();
    if (n < N) {
      if (lane < FN) na[sub][lane] = node_attr[(size_t)n * FN + lane];
      else if (lane < FN + FE) a8[sub][lane - FN] = agg8[(size_t)n * FE + (lane - FN)];
    }
    __syncthreads();
    if (n < N) {
      float acc = b[lane];
#pragma unroll
      for (int k = 0; k < FN; k++) acc += na[sub][k] * Ws[k * H + lane];
#pragma unroll
      for (int k = 0; k < FE; k++) acc += a8[sub][k] * Es[k * H + lane];
      h[(size_t)n * H + lane] = fmaxf(acc, 0.f);
    }
  }
}

// ============================ LDS-free GEMM [N,128]@[128,128]+b ============================
// Thread (c=tid&31, rg=tid>>5): cols 4c..4c+3, rows rg+8i. W read coalesced
// (L1/L2-hot, 64 KB), in read via half-wave-uniform float4 (L1 line reuse
// across 4 consecutive k4). No LDS, no syncs -> FMA-bound.
template <int RELU_OUT>
__global__ __launch_bounds__(256) void k_gemm(
    const float* __restrict__ in, const float* __restrict__ W,
    const float* __restrict__ bias, float* __restrict__ out, int N) {
  int tid = threadIdx.x;
  int c = tid & 31;
  int rg = tid >> 5;
  int rowBase = blockIdx.x * 64;
  const float4* W4 = (const float4*)W;     // [128][32]
  const float4* in4 = (const float4*)in;   // [N][32]
  float4 acc[8];
#pragma unroll
  for (int i = 0; i < 8; i++) acc[i] = make_float4(0.f, 0.f, 0.f, 0.f);
  int r[8];
#pragma unroll
  for (int i = 0; i < 8; i++) {
    int rr = rowBase + rg + 8 * i;
    r[i] = (rr < N) ? rr : (N - 1);   // clamp for safe loads; store guarded below
  }
#pragma unroll 2
  for (int k4 = 0; k4 < 32; k4++) {
    float4 w0 = W4[(k4 * 4 + 0) * 32 + c];
    float4 w1 = W4[(k4 * 4 + 1) * 32 + c];
    float4 w2 = W4[(k4 * 4 + 2) * 32 + c];
    float4 w3 = W4[(k4 * 4 + 3) * 32 + c];
#pragma unroll
    for (int i = 0; i < 8; i++) {
      float4 hv = in4[(size_t)r[i] * 32 + k4];
      acc[i].x += hv.x * w0.x + hv.y * w1.x + hv.z * w2.x + hv.w * w3.x;
      acc[i].y += hv.x * w0.y + hv.y * w1.y + hv.z * w2.y + hv.w * w3.y;
      acc[i].z += hv.x * w0.z + hv.y * w1.z + hv.z * w2.z + hv.w * w3.z;
      acc[i].w += hv.x * w0.w + hv.y * w1.w + hv.z * w2.w + hv.w * w3.w;
    }
  }
  float4 bv = ((const float4*)bias)[c];
#pragma unroll
  for (int i = 0; i < 8; i++) {
    int row = rowBase + rg + 8 * i;
    if (row < N) {
      float4 o = make_float4(acc[i].x + bv.x, acc[i].y + bv.y,
                             acc[i].z + bv.z, acc[i].w + bv.w);
      if (RELU_OUT) {
        o.x = fmaxf(o.x, 0.f); o.y = fmaxf(o.y, 0.f);
        o.z = fmaxf(o.z, 0.f); o.w = fmaxf(o.w, 0.f);
      }
      ((float4*)(out + (size_t)row * H))[c] = o;
    }
  }
}

// ============================ GCN gather-aggregate ============================
__global__ __launch_bounds__(256) void k_gcn_gather(
    const float* __restrict__ hw, const int* __restrict__ offs,
    const int2* __restrict__ pay, float* __restrict__ out, int N) {
  int n = blockIdx.x * 8 + (threadIdx.x >> 5);
  if (n >= N) return;
  int c = threadIdx.x & 31;
  int s = offs[n], t = offs[n + 1];
  float4 acc = make_float4(0.f, 0.f, 0.f, 0.f);
  for (int i = s; i < t; i++) {
    int2 p = pay[i];
    float v = __int_as_float(p.y);
    float4 hv = ((const float4*)hw)[(size_t)p.x * 32 + c];
    acc.x += v * hv.x; acc.y += v * hv.y;
    acc.z += v * hv.z; acc.w += v * hv.w;
  }
  float4 o = make_float4(fmaxf(acc.x, 0.f), fmaxf(acc.y, 0.f),
                         fmaxf(acc.z, 0.f), fmaxf(acc.w, 0.f));
  ((float4*)(out + (size_t)n * H))[c] = o;
}

// ============================ pool + predictor ============================
__global__ __launch_bounds__(256) void k_gbounds(
    const int* __restrict__ batch, int* __restrict__ gstart, int N, int G) {
  int n = blockIdx.x * 256 + threadIdx.x;
  if (n > N) return;
  if (n == 0) {
    for (int g = 0; g <= batch[0]; g++) gstart[g] = 0;
  } else if (n == N) {
    for (int g = batch[N - 1] + 1; g <= G; g++) gstart[g] = N;
  } else {
    int b0 = batch[n - 1], b1 = batch[n];
    for (int g = b0 + 1; g <= b1; g++) gstart[g] = n;
  }
}

__global__ __launch_bounds__(128) void k_pool_seg(
    const float* __restrict__ h, const int* __restrict__ gstart,
    float* __restrict__ fp, int G) {
  int g = blockIdx.x;
  int j = threadIdx.x;
  int s = gstart[g], t = gstart[g + 1];
  float acc = 0.f;
  for (int n = s; n < t; n++) acc += h[(size_t)n * H + j];
  fp[(size_t)g * H + j] = acc;
}

// out[g] = z[g] . Wp2 + bp2  (z precomputed by k_gemm<1>)
__global__ __launch_bounds__(256) void k_pred2(
    const float* __restrict__ z, const float* __restrict__ Wp2,
    const float* __restrict__ bp2, float* __restrict__ out, int G) {
  int g = blockIdx.x * 4 + (threadIdx.x >> 6);
  if (g >= G) return;
  int l = threadIdx.x & 63;
  float2 zv = ((const float2*)z)[(size_t)g * 64 + l];
  float2 wv = ((const float2*)Wp2)[l];
  float v = zv.x * wv.x + zv.y * wv.y;
#pragma unroll
  for (int off = 32; off > 0; off >>= 1) v += __shfl_down(v, off, 64);
  if (l == 0) out[g] = v + bp2[0];
}

// ============================ launch ============================
extern "C" void kernel_launch(void* const* d_in, const int* in_sizes, int n_in,
                              void* d_out, int out_size, void* d_ws, size_t ws_size,
                              hipStream_t stream) {
  const float* node_attr  = (const float*)d_in[0];
  const float* edge_attr  = (const float*)d_in[1];
  const int*   edge_index = (const int*)d_in[2];
  const int*   adj_index  = (const int*)d_in[3];
  const float* adj_value  = (const float*)d_in[4];
  const int*   batch      = (const int*)d_in[5];
  const float* W_node  = (const float*)d_in[6];
  const float* W_edge  = (const float*)d_in[7];
  const float* b_embed = (const float*)d_in[8];
  const float* W1 = (const float*)d_in[9];
  const float* b1 = (const float*)d_in[10];
  const float* W2 = (const float*)d_in[11];
  const float* b2 = (const float*)d_in[12];
  const float* W3 = (const float*)d_in[13];
  const float* b3 = (const float*)d_in[14];
  const float* Wp1 = (const float*)d_in[15];
  const float* bp1 = (const float*)d_in[16];
  const float* Wp2 = (const float*)d_in[17];
  const float* bp2 = (const float*)d_in[18];
  float* out = (float*)d_out;

  const int E = in_sizes[4];           // 1,600,000
  const int N = in_sizes[5];           // 100,000
  const int G = out_size;              // 2048
  const int nbuk = (N + 63) >> 6;      // 1563
  const int p1b = (E + 8191) / 8192;

  // ---- workspace layout ----
  float* A     = (float*)d_ws;                       // N*H
  float* B     = A + (size_t)N * H;                  // N*H
  int2*  payF  = (int2*)(B + (size_t)N * H);         // E
  float* fpool = (float*)(payF + E);                 // G*H
  int*   bcnt1 = (int*)(fpool + (size_t)G * H);      // nbuk  } one memset
  int*   bcnt2 = bcnt1 + nbuk;                       // nbuk  }
  int*   bst1  = bcnt2 + nbuk;                       // nbuk+1
  int*   gcur1 = bst1 + nbuk + 1;                    // nbuk
  int*   bst2  = gcur1 + nbuk;                       // nbuk+1
  int*   gcur2 = bst2 + nbuk + 1;                    // nbuk
  int*   offs2 = gcur2 + nbuk;                       // N+1
  int*   gstart= offs2 + N + 1;                      // G+1
  // transient aliases (lifetimes by launch order):
  float* agg8  = A;                                  // N*FE; dead after embed_h (gemm1 writes A later)
  int*   pkey  = (int*)B;                            // E ints; dead after embed_agg
  int2*  bpay2 = (int2*)(((int*)B) + E);             // E int2; dead after p2 (before embed_h writes B)
  float* zbuf  = A;                                  // G*H; A free after last gather

  // ---- histograms + scans (both sorts) ----
  hipMemsetAsync(bcnt1, 0, (size_t)2 * nbuk * sizeof(int), stream);
  k_hist2<<<512, 256, 0, stream>>>(edge_index + E, adj_index, bcnt1, bcnt2, E, nbuk);
  k_scan<<<1, 1024, 0, stream>>>(bcnt1, bst1, gcur1, bcnt2, bst2, gcur2, nbuk);

  // ---- pass-1 scatters ----
  k_p1_scatter<1><<<p1b, 256, 0, stream>>>(edge_index + E, nullptr, nullptr,
                                           gcur1, pkey, nullptr, E, nbuk);
  k_p1_scatter<0><<<p1b, 256, 0, stream>>>(adj_index, adj_index + E, adj_value,
                                           gcur2, nullptr, bpay2, E, nbuk);

  // ---- embed agg + adj pass-2 (both consume B-region; must precede embed_h) ----
  k_embed_agg<<<nbuk, 256, 0, stream>>>(pkey, edge_attr, bst1, agg8, N);
  k_p2<<<nbuk, 256, 0, stream>>>(bpay2, bst2, offs2, payF, N, E);

  // ---- embed h -> B ----
  k_embed_h<<<4096, 256, 0, stream>>>(node_attr, W_node, W_edge, b_embed, agg8, B, N);

  k_gbounds<<<(N + 256) / 256, 256, 0, stream>>>(batch, gstart, N, G);

  // ---- 3 GCN layers: A = B@W+b ; B = relu(gather(A)) ----
  int gemm_blocks = (N + 63) / 64;
  int agb = (N + 7) / 8;
  k_gemm<0><<<gemm_blocks, 256, 0, stream>>>(B, W1, b1, A, N);
  k_gcn_gather<<<agb, 256, 0, stream>>>(A, offs2, payF, B, N);
  k_gemm<0><<<gemm_blocks, 256, 0, stream>>>(B, W2, b2, A, N);
  k_gcn_gather<<<agb, 256, 0, stream>>>(A, offs2, payF, B, N);
  k_gemm<0><<<gemm_blocks, 256, 0, stream>>>(B, W3, b3, A, N);
  k_gcn_gather<<<agb, 256, 0, stream>>>(A, offs2, payF, B, N);

  // ---- pool + predictor (z = relu(fpool@Wp1+bp1) via gemm, then dot) ----
  k_pool_seg<<<G, 128, 0, stream>>>(B, gstart, fpool, G);
  k_gemm<1><<<G / 64, 256, 0, stream>>>(fpool, Wp1, bp1, zbuf, G);
  k_pred2<<<(G + 3) / 4, 256, 0, stream>>>(zbuf, Wp2, bp2, out, G);
}